// Round 10
// baseline (155.358 us; speedup 1.0000x reference)
//
#include <hip/hip_runtime.h>
#include <math.h>

#define BATCH 16384

typedef float v2f __attribute__((ext_vector_type(2)));

__device__ __forceinline__ v2f pk_fma(v2f a, v2f b, v2f c) {
  return __builtin_elementwise_fma(a, b, c);   // -> v_pk_fma_f32
}
__device__ __forceinline__ v2f pk_max(v2f a, v2f b) {
  return __builtin_elementwise_max(a, b);      // -> v_pk_max_f32
}

// RNE-pack two floats into a bf16 pair (lo -> low16, hi -> high16)
__device__ __forceinline__ unsigned bf2(float lo, float hi) {
  unsigned a = __float_as_uint(lo);
  unsigned b = __float_as_uint(hi);
  a = (a + 0x7fffu + ((a >> 16) & 1u)) >> 16;
  b = (b + 0x7fffu + ((b >> 16) & 1u)) & 0xffff0000u;
  return a | b;
}

// v10 = v8 (best known: 4 samples/wave, fp32 h2, full prefetch incl. edges,
// bf16 plw in LDS, batched tail) + fused BN epilogue via last-block pattern
// (device-scope fences; no dispatch-order assumption). Single kernel.
__global__ __launch_bounds__(256) void qnat_fused(
    const float* __restrict__ x,    // (B,1,28,28)
    const float* __restrict__ w1,   // (4,1,3,3)  uniform -> s_load
    const float* __restrict__ b1,   // (4,)
    const float* __restrict__ w2,   // (4,4,3,3)  uniform -> s_load
    const float* __restrict__ b2,   // (4,)
    const float* __restrict__ plw,  // (16,196)
    const float* __restrict__ plb,  // (16,)
    const float* __restrict__ rw,   // (4,4)
    const float* __restrict__ rb,   // (4,)
    const float* __restrict__ bnw,  // (4,)
    const float* __restrict__ bnb,  // (4,)
    float* __restrict__ pre,        // (B,4) pre-BN output (in d_out), normalized by last block
    float* __restrict__ stats,      // [8] {sum_c, sumsq_c} (in d_ws, zeroed)
    unsigned* __restrict__ counter) // [1] block-completion ticket (in d_ws, zeroed)
{
  // per-wave h1p: 4 ch x (16 rows x 18 cols) fp32, ch stride 288; data col c
  // at stored c+1 (rows 0,15 / cols 0,15 zero pads persist across iterations).
  __shared__ __align__(16) float h1p[4][4 * 288 + 16];
  // per-wave h2: 4 sample slots x 200 fp32 (196 data + 4 zero pad)
  __shared__ __align__(16) float h2[4][4][200];
  // block-shared transposed bf16 plw: row t (f=8t..8t+7) x 16 k-columns
  __shared__ __align__(16) uint4 plw_tb[25 * 16];
  __shared__ float s_red[4][8];
  __shared__ int s_last;

  const int tid = threadIdx.x;
  const int w = tid >> 6;
  const int lane = tid & 63;
  const int base = (blockIdx.x * 4 + w) * 4;    // first of 4 samples

  // ---- stage plw -> plw_tb (bf16, transposed), once per block ----
  #pragma unroll
  for (int j = 0; j < 2; j++) {
    int s = tid + 256 * j;
    if (s < 400) {
      int tp = s >> 4;                // 0..24
      int k = s & 15;
      const float4* pr = (const float4*)(plw + k * 196);
      float4 a = pr[2 * tp];
      float4 b = (tp < 24) ? pr[2 * tp + 1] : make_float4(0.f, 0.f, 0.f, 0.f);
      plw_tb[s] = make_uint4(bf2(a.x, a.y), bf2(a.z, a.w),
                             bf2(b.x, b.y), bf2(b.z, b.w));
    }
  }

  // ---- zero h1p pads + h2 pads (wave-private) ----
  {
    float4 z4 = make_float4(0.f, 0.f, 0.f, 0.f);
    float4* hz = (float4*)&h1p[w][0];
    #pragma unroll
    for (int t = 0; t < 5; t++) {
      int p = t * 64 + lane;
      if (p < 292) hz[p] = z4;
    }
    if (lane < 16) h2[w][lane >> 2][196 + (lane & 3)] = 0.0f;
  }
  __syncthreads();   // plw_tb visible

  const int i = lane >> 2;            // conv1: pooled row 0..13
  const int q = lane & 3;             // conv1: col quad
  const bool c1act = lane < 56;

  // prefetch buffers for conv1 windows (cols 8q-1 .. 8q+8 fully covered)
  float4 pfa[4], pfb[4];
  float pe0[4], pe1[4];
  #pragma unroll
  for (int r = 0; r < 4; r++) {
    pfa[r] = make_float4(0,0,0,0); pfb[r] = make_float4(0,0,0,0);
    pe0[r] = 0.0f; pe1[r] = 0.0f;
  }

  if (c1act) {
    const float* xb = x + (size_t)base * 784;
    #pragma unroll
    for (int r = 0; r < 4; r++) {
      int row = 2 * i - 1 + r;
      if (0 <= row && row < 28) {
        const float* rp = xb + row * 28;
        pfa[r] = *(const float4*)(rp + 8 * q);
        if (q > 0) pe0[r] = rp[8 * q - 1];
        if (q < 3) {
          pfb[r] = *(const float4*)(rp + 8 * q + 4);
          pe1[r] = rp[8 * q + 8];
        }
      }
    }
  }

  // ================= stage 1: conv both layers for 4 samples =================
  for (int it = 0; it < 4; ++it) {
    // ---- conv1 + relu + pool ----
    if (c1act) {
      float win[4][10];               // win[r][k] <-> input col 8q-1+k
      #pragma unroll
      for (int r = 0; r < 4; r++) {
        win[r][0] = pe0[r];
        win[r][1] = pfa[r].x; win[r][2] = pfa[r].y;
        win[r][3] = pfa[r].z; win[r][4] = pfa[r].w;
        win[r][5] = pfb[r].x; win[r][6] = pfb[r].y;
        win[r][7] = pfb[r].z; win[r][8] = pfb[r].w;
        win[r][9] = pe1[r];
      }
      // prefetch next sample's rows while conv1 FMAs run
      if (it != 3) {
        const float* xn = x + (size_t)(base + it + 1) * 784;
        #pragma unroll
        for (int r = 0; r < 4; r++) {
          int row = 2 * i - 1 + r;
          pfa[r] = make_float4(0,0,0,0);
          pfb[r] = make_float4(0,0,0,0);
          pe0[r] = 0.0f; pe1[r] = 0.0f;
          if (0 <= row && row < 28) {
            const float* rp = xn + row * 28;
            pfa[r] = *(const float4*)(rp + 8 * q);
            if (q > 0) pe0[r] = rp[8 * q - 1];
            if (q < 3) {
              pfb[r] = *(const float4*)(rp + 8 * q + 4);
              pe1[r] = rp[8 * q + 8];
            }
          }
        }
      }
      v2f P[4][9];
      #pragma unroll
      for (int r = 0; r < 4; r++)
        #pragma unroll
        for (int k = 0; k < 9; k++) P[r][k] = (v2f){win[r][k], win[r][k + 1]};

      float* hb = &h1p[w][18 * (i + 1) + 1 + 4 * q];
      #pragma unroll
      for (int c = 0; c < 4; c++) {
        const float* wc = w1 + c * 9;
        const v2f bias2 = (v2f){b1[c], b1[c]};
        v2f a0[4], a1[4];
        #pragma unroll
        for (int jj = 0; jj < 4; jj++) { a0[jj] = bias2; a1[jj] = bias2; }
        #pragma unroll
        for (int dy = 0; dy < 3; dy++)
          #pragma unroll
          for (int dx = 0; dx < 3; dx++) {
            const float wv = wc[dy * 3 + dx];
            const v2f wvv = (v2f){wv, wv};
            #pragma unroll
            for (int jj = 0; jj < 4; jj++) {
              a0[jj] = pk_fma(P[dy][2 * jj + dx],     wvv, a0[jj]);
              a1[jj] = pk_fma(P[dy + 1][2 * jj + dx], wvv, a1[jj]);
            }
          }
        float m[4];
        #pragma unroll
        for (int jj = 0; jj < 4; jj++) {
          v2f mm = pk_max(a0[jj], a1[jj]);
          m[jj] = fmaxf(fmaxf(mm.x, mm.y), 0.0f);
        }
        float* p = hb + 288 * c;
        if (q < 3) {
          p[0] = m[0];
          *(float2*)(p + 1) = make_float2(m[1], m[2]);
          p[3] = m[3];
        } else {
          p[0] = m[0];
          p[1] = m[1];
        }
      }
    }
    // h1p wave-private: no barrier.

    // ---- conv2 + relu + pool -> h2[w][it] ----
    {
      const int jq = lane & 7;
      const int i2 = lane >> 3;
      if (i2 < 7 && jq < 7) {
        v2f acc[4][2];
        #pragma unroll
        for (int co = 0; co < 4; co++) {
          const v2f bb = (v2f){b2[co], b2[co]};
          acc[co][0] = bb; acc[co][1] = bb;
        }
        #pragma unroll
        for (int ci = 0; ci < 4; ci++) {
          const float* rp = &h1p[w][288 * ci + 36 * i2 + 2 * jq];
          v2f Q[4][3];
          #pragma unroll
          for (int r = 0; r < 4; r++) {
            v2f a = *(const v2f*)(rp + 18 * r);
            v2f b = *(const v2f*)(rp + 18 * r + 2);
            Q[r][0] = a;
            Q[r][1] = (v2f){a.y, b.x};
            Q[r][2] = b;
          }
          #pragma unroll
          for (int co = 0; co < 4; co++) {
            const float* wp = w2 + (co * 4 + ci) * 9;
            #pragma unroll
            for (int dy = 0; dy < 3; dy++)
              #pragma unroll
              for (int dx = 0; dx < 3; dx++) {
                const float wv = wp[dy * 3 + dx];
                const v2f wvv = (v2f){wv, wv};
                acc[co][0] = pk_fma(Q[dy][dx],     wvv, acc[co][0]);
                acc[co][1] = pk_fma(Q[dy + 1][dx], wvv, acc[co][1]);
              }
          }
        }
        #pragma unroll
        for (int co = 0; co < 4; co++) {
          v2f mm = pk_max(acc[co][0], acc[co][1]);
          h2[w][it][49 * co + 7 * i2 + jq] = fmaxf(fmaxf(mm.x, mm.y), 0.0f);
        }
      }
    }
    // h2 wave-private: no barrier.
  }

  // ============ stage 2: linear + circuit for all 4 samples batched ============
  const int s2 = lane >> 4;           // sample slot 0..3
  const int k = lane & 15;            // param index / amp index

  // ---- linear: one full 196-dot per lane; LDS-only operands ----
  float cv, sv;
  {
    const float4* hv4 = (const float4*)&h2[w][s2][0];   // broadcast, conflict-free
    const uint4*  wb4 = &plw_tb[k];                     // row stride 16 uint4s
    v2f sacc = (v2f){0.0f, 0.0f};
    #pragma unroll
    for (int t = 0; t < 25; t++) {
      float4 h0 = hv4[2 * t];
      float4 h1 = hv4[2 * t + 1];
      uint4 wb = wb4[16 * t];
      v2f w01 = (v2f){__uint_as_float(wb.x << 16), __uint_as_float(wb.x & 0xffff0000u)};
      v2f w23 = (v2f){__uint_as_float(wb.y << 16), __uint_as_float(wb.y & 0xffff0000u)};
      v2f w45 = (v2f){__uint_as_float(wb.z << 16), __uint_as_float(wb.z & 0xffff0000u)};
      v2f w67 = (v2f){__uint_as_float(wb.w << 16), __uint_as_float(wb.w & 0xffff0000u)};
      sacc = pk_fma((v2f){h0.x, h0.y}, w01, sacc);
      sacc = pk_fma((v2f){h0.z, h0.w}, w23, sacc);
      sacc = pk_fma((v2f){h1.x, h1.y}, w45, sacc);
      sacc = pk_fma((v2f){h1.z, h1.w}, w67, sacc);
    }
    float pv = sacc.x + sacc.y + plb[k];
    __sincosf(pv * 0.5f, &sv, &cv);
  }

  // ---- 4-qubit circuit: 4 samples in parallel on 16-lane groups ----
  {
    const int l = k;                  // amp index within group
    const int gb = lane & 48;         // group base for param broadcasts
    float re = (l == 0) ? 1.0f : 0.0f;
    float im = 0.0f;
    #pragma unroll
    for (int qi = 0; qi < 4; qi++) {
      const int beta = 3 - qi;
      const int m = 1 << beta;        // <16: shfl_xor stays in group
      const int b = (l >> beta) & 1;
      float c = __shfl(cv, gb + 4 * qi, 64), s = __shfl(sv, gb + 4 * qi, 64);
      float pr_ = __shfl_xor(re, m, 64), pi_ = __shfl_xor(im, m, 64);
      float sg = b ? s : -s;
      re = fmaf(c, re, sg * pr_);
      im = fmaf(c, im, sg * pi_);
      c = __shfl(cv, gb + 4 * qi + 1, 64); s = __shfl(sv, gb + 4 * qi + 1, 64);
      float sz = b ? s : -s;
      float nr = c * re - sz * im;
      float ni = c * im + sz * re;
      re = nr; im = ni;
      c = __shfl(cv, gb + 4 * qi + 2, 64); s = __shfl(sv, gb + 4 * qi + 2, 64);
      pr_ = __shfl_xor(re, m, 64); pi_ = __shfl_xor(im, m, 64);
      nr = fmaf(c, re, s * pi_);
      ni = fmaf(c, im, -s * pr_);
      re = nr; im = ni;
      const int tm = 1 << (3 - ((qi + 1) & 3));   // <16: in-group
      float fr = __shfl_xor(re, tm, 64), fi = __shfl_xor(im, tm, 64);
      if (b) { re = fr; im = fi; }
    }
    float pr2 = re * re + im * im;
    float z0 = ((l >> 3) & 1) ? -pr2 : pr2;
    float z1 = ((l >> 2) & 1) ? -pr2 : pr2;
    float z2 = ((l >> 1) & 1) ? -pr2 : pr2;
    float z3 = (l & 1) ? -pr2 : pr2;
    #pragma unroll
    for (int off = 8; off >= 1; off >>= 1) {      // in-group reductions
      z0 += __shfl_xor(z0, off, 64);
      z1 += __shfl_xor(z1, off, 64);
      z2 += __shfl_xor(z2, off, 64);
      z3 += __shfl_xor(z3, off, 64);
    }
    float as0 = 0.f, as1 = 0.f, as2 = 0.f, as3 = 0.f;
    float aq0 = 0.f, aq1 = 0.f, aq2 = 0.f, aq3 = 0.f;
    if (l == 0) {                     // lanes 0,16,32,48: one sample each
      float o0 = fmaf(rw[0],  z0, fmaf(rw[1],  z1, fmaf(rw[2],  z2, fmaf(rw[3],  z3, rb[0]))));
      float o1 = fmaf(rw[4],  z0, fmaf(rw[5],  z1, fmaf(rw[6],  z2, fmaf(rw[7],  z3, rb[1]))));
      float o2 = fmaf(rw[8],  z0, fmaf(rw[9],  z1, fmaf(rw[10], z2, fmaf(rw[11], z3, rb[2]))));
      float o3 = fmaf(rw[12], z0, fmaf(rw[13], z1, fmaf(rw[14], z2, fmaf(rw[15], z3, rb[3]))));
      *(float4*)(pre + (size_t)(base + s2) * 4) = make_float4(o0, o1, o2, o3);
      as0 = o0; aq0 = o0 * o0;
      as1 = o1; aq1 = o1 * o1;
      as2 = o2; aq2 = o2 * o2;
      as3 = o3; aq3 = o3 * o3;
    }
    #pragma unroll
    for (int off = 32; off >= 16; off >>= 1) {
      as0 += __shfl_down(as0, off, 64); aq0 += __shfl_down(aq0, off, 64);
      as1 += __shfl_down(as1, off, 64); aq1 += __shfl_down(aq1, off, 64);
      as2 += __shfl_down(as2, off, 64); aq2 += __shfl_down(aq2, off, 64);
      as3 += __shfl_down(as3, off, 64); aq3 += __shfl_down(aq3, off, 64);
    }
    if (lane == 0) {
      s_red[w][0] = as0; s_red[w][4] = aq0;
      s_red[w][1] = as1; s_red[w][5] = aq1;
      s_red[w][2] = as2; s_red[w][6] = aq2;
      s_red[w][3] = as3; s_red[w][7] = aq3;
    }
  }
  __syncthreads();
  if (tid < 8) {
    float v = s_red[0][tid] + s_red[1][tid] + s_red[2][tid] + s_red[3][tid];
    atomicAdd(&stats[tid], v);
  }

  // ============ fused BN epilogue: last finishing block normalizes ============
  if (tid == 0) {
    __threadfence();                          // release: pre writes + stats visible device-wide
    unsigned t = atomicAdd(counter, 1u);
    s_last = (t == gridDim.x - 1) ? 1 : 0;
  }
  __syncthreads();
  if (s_last) {
    __threadfence();                          // acquire: see all blocks' pre/stats
    const float invB = 1.0f / BATCH;
    float mean[4], inv[4], g[4], bta[4];
    #pragma unroll
    for (int c = 0; c < 4; c++) {
      mean[c] = stats[c] * invB;
      float var = stats[4 + c] * invB - mean[c] * mean[c];
      inv[c] = rsqrtf(var + 1e-5f) * bnw[c];
      g[c] = bnb[c];
      bta[c] = g[c] - mean[c] * inv[c];       // out = pre*inv + bta
    }
    float4* o4 = (float4*)pre;
    for (int p = tid; p < BATCH; p += 256) {
      float4 v = o4[p];
      v.x = fmaf(v.x, inv[0], bta[0]);
      v.y = fmaf(v.y, inv[1], bta[1]);
      v.z = fmaf(v.z, inv[2], bta[2]);
      v.w = fmaf(v.w, inv[3], bta[3]);
      o4[p] = v;
    }
  }
}

extern "C" void kernel_launch(void* const* d_in, const int* in_sizes, int n_in,
                              void* d_out, int out_size, void* d_ws, size_t ws_size,
                              hipStream_t stream) {
  const float* x   = (const float*)d_in[0];
  const float* w1  = (const float*)d_in[1];
  const float* b1  = (const float*)d_in[2];
  const float* w2  = (const float*)d_in[3];
  const float* b2  = (const float*)d_in[4];
  const float* plw = (const float*)d_in[5];
  const float* plb = (const float*)d_in[6];
  const float* rw  = (const float*)d_in[7];
  const float* rb  = (const float*)d_in[8];
  const float* bnw = (const float*)d_in[9];
  const float* bnb = (const float*)d_in[10];

  float* out = (float*)d_out;
  float* stats = (float*)d_ws;                      // 8 floats
  unsigned* counter = (unsigned*)((char*)d_ws + 32); // 1 uint

  hipMemsetAsync(d_ws, 0, 64, stream);
  qnat_fused<<<BATCH / 16, 256, 0, stream>>>(x, w1, b1, w2, b2, plw, plb, rw, rb,
                                             bnw, bnb, out, stats, counter);
}

// Round 11
// 132.559 us; speedup vs baseline: 1.1720x; 1.1720x over previous
//
#include <hip/hip_runtime.h>
#include <math.h>

#define BATCH 16384

typedef float v2f __attribute__((ext_vector_type(2)));

__device__ __forceinline__ v2f pk_fma(v2f a, v2f b, v2f c) {
  return __builtin_elementwise_fma(a, b, c);   // -> v_pk_fma_f32
}
__device__ __forceinline__ v2f pk_max(v2f a, v2f b) {
  return __builtin_elementwise_max(a, b);      // -> v_pk_max_f32
}

// RNE-pack two floats into a bf16 pair (lo -> low16, hi -> high16)
__device__ __forceinline__ unsigned bf2(float lo, float hi) {
  unsigned a = __float_as_uint(lo);
  unsigned b = __float_as_uint(hi);
  a = (a + 0x7fffu + ((a >> 16) & 1u)) >> 16;
  b = (b + 0x7fffu + ((b >> 16) & 1u)) & 0xffff0000u;
  return a | b;
}

// v11 = v8 restored (best measured: fused 46.5us, total 134.2us).
// Lessons locked in from failed R9/R10: VGPR=72 is irreducible (>64 cliff ->
// 16 waves/CU cap); device-scope fence per block (~28us aggregate) costs more
// than the separate 4us BN kernel; harness overhead (~85us) is dispatch-count
// invariant. 4 samples/wave, full prefetch, bf16 plw in LDS, batched tail.
__global__ __launch_bounds__(256) void qnat_fused(
    const float* __restrict__ x,    // (B,1,28,28)
    const float* __restrict__ w1,   // (4,1,3,3)  uniform -> s_load
    const float* __restrict__ b1,   // (4,)
    const float* __restrict__ w2,   // (4,4,3,3)  uniform -> s_load
    const float* __restrict__ b2,   // (4,)
    const float* __restrict__ plw,  // (16,196)
    const float* __restrict__ plb,  // (16,)
    const float* __restrict__ rw,   // (4,4)
    const float* __restrict__ rb,   // (4,)
    float* __restrict__ pre,        // (B,4) pre-BN output (in d_out)
    float* __restrict__ stats)      // [8] {sum_c, sumsq_c}
{
  // per-wave h1p: 4 ch x (16 rows x 18 cols) fp32, ch stride 288; data col c
  // at stored c+1 (rows 0,15 / cols 0,15 zero pads persist across iterations).
  __shared__ __align__(16) float h1p[4][4 * 288 + 16];
  // per-wave h2: 4 sample slots x 200 fp32 (196 data + 4 zero pad)
  __shared__ __align__(16) float h2[4][4][200];
  // block-shared transposed bf16 plw: row t (f=8t..8t+7) x 16 k-columns
  __shared__ __align__(16) uint4 plw_tb[25 * 16];
  __shared__ float s_red[4][8];

  const int tid = threadIdx.x;
  const int w = tid >> 6;
  const int lane = tid & 63;
  const int base = (blockIdx.x * 4 + w) * 4;    // first of 4 samples

  // ---- stage plw -> plw_tb (bf16, transposed), once per block ----
  #pragma unroll
  for (int j = 0; j < 2; j++) {
    int s = tid + 256 * j;
    if (s < 400) {
      int tp = s >> 4;                // 0..24
      int k = s & 15;
      const float4* pr = (const float4*)(plw + k * 196);
      float4 a = pr[2 * tp];
      float4 b = (tp < 24) ? pr[2 * tp + 1] : make_float4(0.f, 0.f, 0.f, 0.f);
      plw_tb[s] = make_uint4(bf2(a.x, a.y), bf2(a.z, a.w),
                             bf2(b.x, b.y), bf2(b.z, b.w));
    }
  }

  // ---- zero h1p pads + h2 pads (wave-private) ----
  {
    float4 z4 = make_float4(0.f, 0.f, 0.f, 0.f);
    float4* hz = (float4*)&h1p[w][0];
    #pragma unroll
    for (int t = 0; t < 5; t++) {
      int p = t * 64 + lane;
      if (p < 292) hz[p] = z4;
    }
    if (lane < 16) h2[w][lane >> 2][196 + (lane & 3)] = 0.0f;
  }
  __syncthreads();   // plw_tb visible

  const int i = lane >> 2;            // conv1: pooled row 0..13
  const int q = lane & 3;             // conv1: col quad
  const bool c1act = lane < 56;

  // prefetch buffers for conv1 windows (cols 8q-1 .. 8q+8 fully covered)
  float4 pfa[4], pfb[4];
  float pe0[4], pe1[4];
  #pragma unroll
  for (int r = 0; r < 4; r++) {
    pfa[r] = make_float4(0,0,0,0); pfb[r] = make_float4(0,0,0,0);
    pe0[r] = 0.0f; pe1[r] = 0.0f;
  }

  if (c1act) {
    const float* xb = x + (size_t)base * 784;
    #pragma unroll
    for (int r = 0; r < 4; r++) {
      int row = 2 * i - 1 + r;
      if (0 <= row && row < 28) {
        const float* rp = xb + row * 28;
        pfa[r] = *(const float4*)(rp + 8 * q);
        if (q > 0) pe0[r] = rp[8 * q - 1];
        if (q < 3) {
          pfb[r] = *(const float4*)(rp + 8 * q + 4);
          pe1[r] = rp[8 * q + 8];
        }
      }
    }
  }

  // ================= stage 1: conv both layers for 4 samples =================
  for (int it = 0; it < 4; ++it) {
    // ---- conv1 + relu + pool ----
    if (c1act) {
      float win[4][10];               // win[r][k] <-> input col 8q-1+k
      #pragma unroll
      for (int r = 0; r < 4; r++) {
        win[r][0] = pe0[r];
        win[r][1] = pfa[r].x; win[r][2] = pfa[r].y;
        win[r][3] = pfa[r].z; win[r][4] = pfa[r].w;
        win[r][5] = pfb[r].x; win[r][6] = pfb[r].y;
        win[r][7] = pfb[r].z; win[r][8] = pfb[r].w;
        win[r][9] = pe1[r];
      }
      // prefetch next sample's rows while conv1 FMAs run
      if (it != 3) {
        const float* xn = x + (size_t)(base + it + 1) * 784;
        #pragma unroll
        for (int r = 0; r < 4; r++) {
          int row = 2 * i - 1 + r;
          pfa[r] = make_float4(0,0,0,0);
          pfb[r] = make_float4(0,0,0,0);
          pe0[r] = 0.0f; pe1[r] = 0.0f;
          if (0 <= row && row < 28) {
            const float* rp = xn + row * 28;
            pfa[r] = *(const float4*)(rp + 8 * q);
            if (q > 0) pe0[r] = rp[8 * q - 1];
            if (q < 3) {
              pfb[r] = *(const float4*)(rp + 8 * q + 4);
              pe1[r] = rp[8 * q + 8];
            }
          }
        }
      }
      v2f P[4][9];
      #pragma unroll
      for (int r = 0; r < 4; r++)
        #pragma unroll
        for (int k = 0; k < 9; k++) P[r][k] = (v2f){win[r][k], win[r][k + 1]};

      float* hb = &h1p[w][18 * (i + 1) + 1 + 4 * q];
      #pragma unroll
      for (int c = 0; c < 4; c++) {
        const float* wc = w1 + c * 9;
        const v2f bias2 = (v2f){b1[c], b1[c]};
        v2f a0[4], a1[4];
        #pragma unroll
        for (int jj = 0; jj < 4; jj++) { a0[jj] = bias2; a1[jj] = bias2; }
        #pragma unroll
        for (int dy = 0; dy < 3; dy++)
          #pragma unroll
          for (int dx = 0; dx < 3; dx++) {
            const float wv = wc[dy * 3 + dx];
            const v2f wvv = (v2f){wv, wv};
            #pragma unroll
            for (int jj = 0; jj < 4; jj++) {
              a0[jj] = pk_fma(P[dy][2 * jj + dx],     wvv, a0[jj]);
              a1[jj] = pk_fma(P[dy + 1][2 * jj + dx], wvv, a1[jj]);
            }
          }
        float m[4];
        #pragma unroll
        for (int jj = 0; jj < 4; jj++) {
          v2f mm = pk_max(a0[jj], a1[jj]);
          m[jj] = fmaxf(fmaxf(mm.x, mm.y), 0.0f);
        }
        float* p = hb + 288 * c;
        if (q < 3) {
          p[0] = m[0];
          *(float2*)(p + 1) = make_float2(m[1], m[2]);
          p[3] = m[3];
        } else {
          p[0] = m[0];
          p[1] = m[1];
        }
      }
    }
    // h1p wave-private: no barrier.

    // ---- conv2 + relu + pool -> h2[w][it] ----
    {
      const int jq = lane & 7;
      const int i2 = lane >> 3;
      if (i2 < 7 && jq < 7) {
        v2f acc[4][2];
        #pragma unroll
        for (int co = 0; co < 4; co++) {
          const v2f bb = (v2f){b2[co], b2[co]};
          acc[co][0] = bb; acc[co][1] = bb;
        }
        #pragma unroll
        for (int ci = 0; ci < 4; ci++) {
          const float* rp = &h1p[w][288 * ci + 36 * i2 + 2 * jq];
          v2f Q[4][3];
          #pragma unroll
          for (int r = 0; r < 4; r++) {
            v2f a = *(const v2f*)(rp + 18 * r);
            v2f b = *(const v2f*)(rp + 18 * r + 2);
            Q[r][0] = a;
            Q[r][1] = (v2f){a.y, b.x};
            Q[r][2] = b;
          }
          #pragma unroll
          for (int co = 0; co < 4; co++) {
            const float* wp = w2 + (co * 4 + ci) * 9;
            #pragma unroll
            for (int dy = 0; dy < 3; dy++)
              #pragma unroll
              for (int dx = 0; dx < 3; dx++) {
                const float wv = wp[dy * 3 + dx];
                const v2f wvv = (v2f){wv, wv};
                acc[co][0] = pk_fma(Q[dy][dx],     wvv, acc[co][0]);
                acc[co][1] = pk_fma(Q[dy + 1][dx], wvv, acc[co][1]);
              }
          }
        }
        #pragma unroll
        for (int co = 0; co < 4; co++) {
          v2f mm = pk_max(acc[co][0], acc[co][1]);
          h2[w][it][49 * co + 7 * i2 + jq] = fmaxf(fmaxf(mm.x, mm.y), 0.0f);
        }
      }
    }
    // h2 wave-private: no barrier.
  }

  // ============ stage 2: linear + circuit for all 4 samples batched ============
  const int s2 = lane >> 4;           // sample slot 0..3
  const int k = lane & 15;            // param index / amp index

  // ---- linear: one full 196-dot per lane; LDS-only operands ----
  float cv, sv;
  {
    const float4* hv4 = (const float4*)&h2[w][s2][0];   // broadcast, conflict-free
    const uint4*  wb4 = &plw_tb[k];                     // row stride 16 uint4s
    v2f sacc = (v2f){0.0f, 0.0f};
    #pragma unroll
    for (int t = 0; t < 25; t++) {
      float4 h0 = hv4[2 * t];
      float4 h1 = hv4[2 * t + 1];
      uint4 wb = wb4[16 * t];
      v2f w01 = (v2f){__uint_as_float(wb.x << 16), __uint_as_float(wb.x & 0xffff0000u)};
      v2f w23 = (v2f){__uint_as_float(wb.y << 16), __uint_as_float(wb.y & 0xffff0000u)};
      v2f w45 = (v2f){__uint_as_float(wb.z << 16), __uint_as_float(wb.z & 0xffff0000u)};
      v2f w67 = (v2f){__uint_as_float(wb.w << 16), __uint_as_float(wb.w & 0xffff0000u)};
      sacc = pk_fma((v2f){h0.x, h0.y}, w01, sacc);
      sacc = pk_fma((v2f){h0.z, h0.w}, w23, sacc);
      sacc = pk_fma((v2f){h1.x, h1.y}, w45, sacc);
      sacc = pk_fma((v2f){h1.z, h1.w}, w67, sacc);
    }
    float pv = sacc.x + sacc.y + plb[k];
    __sincosf(pv * 0.5f, &sv, &cv);
  }

  // ---- 4-qubit circuit: 4 samples in parallel on 16-lane groups ----
  {
    const int l = k;                  // amp index within group
    const int gb = lane & 48;         // group base for param broadcasts
    float re = (l == 0) ? 1.0f : 0.0f;
    float im = 0.0f;
    #pragma unroll
    for (int qi = 0; qi < 4; qi++) {
      const int beta = 3 - qi;
      const int m = 1 << beta;        // <16: shfl_xor stays in group
      const int b = (l >> beta) & 1;
      float c = __shfl(cv, gb + 4 * qi, 64), s = __shfl(sv, gb + 4 * qi, 64);
      float pr_ = __shfl_xor(re, m, 64), pi_ = __shfl_xor(im, m, 64);
      float sg = b ? s : -s;
      re = fmaf(c, re, sg * pr_);
      im = fmaf(c, im, sg * pi_);
      c = __shfl(cv, gb + 4 * qi + 1, 64); s = __shfl(sv, gb + 4 * qi + 1, 64);
      float sz = b ? s : -s;
      float nr = c * re - sz * im;
      float ni = c * im + sz * re;
      re = nr; im = ni;
      c = __shfl(cv, gb + 4 * qi + 2, 64); s = __shfl(sv, gb + 4 * qi + 2, 64);
      pr_ = __shfl_xor(re, m, 64); pi_ = __shfl_xor(im, m, 64);
      nr = fmaf(c, re, s * pi_);
      ni = fmaf(c, im, -s * pr_);
      re = nr; im = ni;
      const int tm = 1 << (3 - ((qi + 1) & 3));   // <16: in-group
      float fr = __shfl_xor(re, tm, 64), fi = __shfl_xor(im, tm, 64);
      if (b) { re = fr; im = fi; }
    }
    float pr2 = re * re + im * im;
    float z0 = ((l >> 3) & 1) ? -pr2 : pr2;
    float z1 = ((l >> 2) & 1) ? -pr2 : pr2;
    float z2 = ((l >> 1) & 1) ? -pr2 : pr2;
    float z3 = (l & 1) ? -pr2 : pr2;
    #pragma unroll
    for (int off = 8; off >= 1; off >>= 1) {      // in-group reductions
      z0 += __shfl_xor(z0, off, 64);
      z1 += __shfl_xor(z1, off, 64);
      z2 += __shfl_xor(z2, off, 64);
      z3 += __shfl_xor(z3, off, 64);
    }
    float as0 = 0.f, as1 = 0.f, as2 = 0.f, as3 = 0.f;
    float aq0 = 0.f, aq1 = 0.f, aq2 = 0.f, aq3 = 0.f;
    if (l == 0) {                     // lanes 0,16,32,48: one sample each
      float o0 = fmaf(rw[0],  z0, fmaf(rw[1],  z1, fmaf(rw[2],  z2, fmaf(rw[3],  z3, rb[0]))));
      float o1 = fmaf(rw[4],  z0, fmaf(rw[5],  z1, fmaf(rw[6],  z2, fmaf(rw[7],  z3, rb[1]))));
      float o2 = fmaf(rw[8],  z0, fmaf(rw[9],  z1, fmaf(rw[10], z2, fmaf(rw[11], z3, rb[2]))));
      float o3 = fmaf(rw[12], z0, fmaf(rw[13], z1, fmaf(rw[14], z2, fmaf(rw[15], z3, rb[3]))));
      *(float4*)(pre + (size_t)(base + s2) * 4) = make_float4(o0, o1, o2, o3);
      as0 = o0; aq0 = o0 * o0;
      as1 = o1; aq1 = o1 * o1;
      as2 = o2; aq2 = o2 * o2;
      as3 = o3; aq3 = o3 * o3;
    }
    #pragma unroll
    for (int off = 32; off >= 16; off >>= 1) {
      as0 += __shfl_down(as0, off, 64); aq0 += __shfl_down(aq0, off, 64);
      as1 += __shfl_down(as1, off, 64); aq1 += __shfl_down(aq1, off, 64);
      as2 += __shfl_down(as2, off, 64); aq2 += __shfl_down(aq2, off, 64);
      as3 += __shfl_down(as3, off, 64); aq3 += __shfl_down(aq3, off, 64);
    }
    if (lane == 0) {
      s_red[w][0] = as0; s_red[w][4] = aq0;
      s_red[w][1] = as1; s_red[w][5] = aq1;
      s_red[w][2] = as2; s_red[w][6] = aq2;
      s_red[w][3] = as3; s_red[w][7] = aq3;
    }
  }
  __syncthreads();
  if (tid < 8) {
    float v = s_red[0][tid] + s_red[1][tid] + s_red[2][tid] + s_red[3][tid];
    atomicAdd(&stats[tid], v);
  }
}

__global__ __launch_bounds__(256) void qnat_bn(
    float* __restrict__ pre,
    const float* __restrict__ stats,
    const float* __restrict__ bnw,
    const float* __restrict__ bnb)
{
  int idx = blockIdx.x * 256 + threadIdx.x;
  int c = idx & 3;
  float mean = stats[c] * (1.0f / BATCH);
  float ex2 = stats[4 + c] * (1.0f / BATCH);
  float var = ex2 - mean * mean;
  float inv = rsqrtf(var + 1e-5f);
  pre[idx] = (pre[idx] - mean) * inv * bnw[c] + bnb[c];
}

extern "C" void kernel_launch(void* const* d_in, const int* in_sizes, int n_in,
                              void* d_out, int out_size, void* d_ws, size_t ws_size,
                              hipStream_t stream) {
  const float* x   = (const float*)d_in[0];
  const float* w1  = (const float*)d_in[1];
  const float* b1  = (const float*)d_in[2];
  const float* w2  = (const float*)d_in[3];
  const float* b2  = (const float*)d_in[4];
  const float* plw = (const float*)d_in[5];
  const float* plb = (const float*)d_in[6];
  const float* rw  = (const float*)d_in[7];
  const float* rb  = (const float*)d_in[8];
  const float* bnw = (const float*)d_in[9];
  const float* bnb = (const float*)d_in[10];

  float* out   = (float*)d_out;
  float* stats = (float*)d_ws;

  hipMemsetAsync(stats, 0, 8 * sizeof(float), stream);
  qnat_fused<<<BATCH / 16, 256, 0, stream>>>(x, w1, b1, w2, b2, plw, plb, rw, rb, out, stats);
  qnat_bn<<<(BATCH * 4) / 256, 256, 0, stream>>>(out, stats, bnw, bnb);
}